// Round 9
// baseline (191.642 us; speedup 1.0000x reference)
//
#include <hip/hip_runtime.h>

// Capsule routing: B=256, J=2, N=6912, E=16, D=8, 2 routing iters. All fp32.
//   pass1: s1[b,j,e] = sum_n u_hat;  v1 = squash(0.5*s1)
//   pass2: l[j,n] = sum_e v1*u_hat; c = sigmoid(l0-l1); s2 = sum_n c*u_hat
//   out = squash(s2) fp32 [256,2,16].
// R9: R8 still latency-bound (VALU 9-16%, VGPR 52-64): 32 W-loads/n clog the
// VMEM queue in ~3-deep batches. Fix: stage the block's 36KB W slice in LDS
// (wave-uniform ds_read broadcast in the FMA loop); the only global loads in
// the hot loop are 18 prefetched per-lane x float4s. LDS reused for the block
// reduction. Non-atomic partials + fused reduce/squash (R8, proven).
#define B_ 256
#define J_ 2
#define N_ 6912
#define E_ 16
#define D_ 8
#define NPW 9     // n per wave
#define NB 36     // n per block (4 waves)
#define CGX 192   // grid (CGX,4); 768 blocks; blockLinear = cx*4 + btile

// ---------------- main path ----------------

// grid (CGX, 4): blockIdx.y = btile (64 b), 4 waves = 4 n-chunks of NPW.
__global__ __launch_bounds__(256, 3) void kpass1(const float* __restrict__ x,
                                                 const float* __restrict__ W,
                                                 float* __restrict__ partial)
{
  __shared__ float smem[9216];   // 36KB: W slice, then reduction scratch
  const int tid  = threadIdx.x;
  const int lane = tid & 63;
  const int wv   = __builtin_amdgcn_readfirstlane(tid >> 6);
  const int b    = blockIdx.y*64 + lane;
  const int nb0  = blockIdx.x * NB;

  // prefetch all 18 x float4s for this lane (HBM stream, deep pipeline)
  const float* xp = x + ((size_t)b*N_ + nb0 + wv*NPW)*D_;
  float4 xa[9], xb[9];
  #pragma unroll
  for (int ni=0; ni<9; ++ni){
    xa[ni] = *(const float4*)(xp + ni*8);
    xb[ni] = *(const float4*)(xp + ni*8 + 4);
  }

  // stage W[j=0..1][nb0..nb0+35][16][8] -> smem (2 contiguous 18KB segments)
  float4 wbuf[9];
  #pragma unroll
  for (int k=0;k<9;++k){
    const int idx = k*256 + tid;            // float4 idx 0..2303
    const int j   = (idx >= 1152) ? 1 : 0;
    const int r4  = idx - j*1152;
    wbuf[k] = *(const float4*)(W + ((size_t)j*N_ + nb0)*(E_*D_) + (size_t)r4*4);
  }
  #pragma unroll
  for (int k=0;k<9;++k)
    *(float4*)(smem + (size_t)(k*256 + tid)*4) = wbuf[k];
  __syncthreads();

  float acc[32];
  #pragma unroll
  for (int i=0;i<32;++i) acc[i]=0.f;

  #pragma unroll
  for (int ni=0; ni<9; ++ni){
    const int nl = wv*NPW + ni;             // local n
    const float4 va = xa[ni], vb = xb[ni];
    #pragma unroll
    for (int j=0;j<J_;++j){
      const float* wp = smem + (j*NB + nl)*(E_*D_);   // wave-uniform: broadcast
      #pragma unroll
      for (int e=0;e<E_;++e){
        const float4 wa = *(const float4*)(wp + e*8);
        const float4 wb = *(const float4*)(wp + e*8 + 4);
        float a = acc[j*16+e];
        a = fmaf(wa.x, va.x, a); a = fmaf(wa.y, va.y, a);
        a = fmaf(wa.z, va.z, a); a = fmaf(wa.w, va.w, a);
        a = fmaf(wb.x, vb.x, a); a = fmaf(wb.y, vb.y, a);
        a = fmaf(wb.z, vb.z, a); a = fmaf(wb.w, vb.w, a);
        acc[j*16+e] = a;
      }
    }
  }

  // block reduction (reuse smem), then coalesced non-atomic partial store
  __syncthreads();
  #pragma unroll
  for (int i=0;i<32;++i) smem[tid*33 + i] = acc[i];
  __syncthreads();
  const int bl = tid >> 2;
  const int i0 = (tid & 3) * 8;
  float v[8];
  #pragma unroll
  for (int k=0;k<8;++k){
    float s = 0.f;
    #pragma unroll
    for (int w=0; w<4; ++w) s += smem[(w*64 + bl)*33 + i0 + k];
    v[k] = s;
  }
  float* dst = partial + (size_t)(blockIdx.x*4 + blockIdx.y)*2048 + bl*32 + i0;
  *(float4*)(dst)     = make_float4(v[0],v[1],v[2],v[3]);
  *(float4*)(dst + 4) = make_float4(v[4],v[5],v[6],v[7]);
}

__global__ __launch_bounds__(256, 3) void kpass2(const float* __restrict__ x,
                                                 const float* __restrict__ W,
                                                 const float* __restrict__ v1,
                                                 float* __restrict__ partial)
{
  __shared__ float smem[9216];
  const int tid  = threadIdx.x;
  const int lane = tid & 63;
  const int wv   = __builtin_amdgcn_readfirstlane(tid >> 6);
  const int b    = blockIdx.y*64 + lane;
  const int nb0  = blockIdx.x * NB;

  const float* xp = x + ((size_t)b*N_ + nb0 + wv*NPW)*D_;
  float4 xa[9], xb[9];
  #pragma unroll
  for (int ni=0; ni<9; ++ni){
    xa[ni] = *(const float4*)(xp + ni*8);
    xb[ni] = *(const float4*)(xp + ni*8 + 4);
  }

  float4 wbuf[9];
  #pragma unroll
  for (int k=0;k<9;++k){
    const int idx = k*256 + tid;
    const int j   = (idx >= 1152) ? 1 : 0;
    const int r4  = idx - j*1152;
    wbuf[k] = *(const float4*)(W + ((size_t)j*N_ + nb0)*(E_*D_) + (size_t)r4*4);
  }
  #pragma unroll
  for (int k=0;k<9;++k)
    *(float4*)(smem + (size_t)(k*256 + tid)*4) = wbuf[k];

  // v1 for this lane's b (loaded after wbuf regs die)
  float vv[32];
  {
    const float4* vp = (const float4*)(v1 + (size_t)b*32);
    #pragma unroll
    for (int q=0;q<8;++q){
      const float4 t4 = vp[q];
      vv[q*4+0]=t4.x; vv[q*4+1]=t4.y; vv[q*4+2]=t4.z; vv[q*4+3]=t4.w;
    }
  }
  __syncthreads();

  float acc[32];
  #pragma unroll
  for (int i=0;i<32;++i) acc[i]=0.f;

  #pragma unroll
  for (int ni=0; ni<9; ++ni){
    const int nl = wv*NPW + ni;
    const float4 va = xa[ni], vb = xb[ni];
    float u[32];
    #pragma unroll
    for (int j=0;j<J_;++j){
      const float* wp = smem + (j*NB + nl)*(E_*D_);
      #pragma unroll
      for (int e=0;e<E_;++e){
        const float4 wa = *(const float4*)(wp + e*8);
        const float4 wb = *(const float4*)(wp + e*8 + 4);
        float a;
        a = wa.x*va.x;           a = fmaf(wa.y, va.y, a);
        a = fmaf(wa.z, va.z, a); a = fmaf(wa.w, va.w, a);
        a = fmaf(wb.x, vb.x, a); a = fmaf(wb.y, vb.y, a);
        a = fmaf(wb.z, vb.z, a); a = fmaf(wb.w, vb.w, a);
        u[j*16+e] = a;
      }
    }
    float l0=0.f, l1=0.f;
    #pragma unroll
    for (int e=0;e<E_;++e){
      l0 = fmaf(vv[e],    u[e],    l0);
      l1 = fmaf(vv[16+e], u[16+e], l1);
    }
    const float c0 = 1.f/(1.f + __expf(l1 - l0));   // softmax over 2 caps
    const float c1 = 1.f - c0;
    #pragma unroll
    for (int e=0;e<E_;++e){
      acc[e]    = fmaf(c0, u[e],    acc[e]);
      acc[16+e] = fmaf(c1, u[16+e], acc[16+e]);
    }
  }

  __syncthreads();
  #pragma unroll
  for (int i=0;i<32;++i) smem[tid*33 + i] = acc[i];
  __syncthreads();
  const int bl = tid >> 2;
  const int i0 = (tid & 3) * 8;
  float v[8];
  #pragma unroll
  for (int k=0;k<8;++k){
    float s = 0.f;
    #pragma unroll
    for (int w=0; w<4; ++w) s += smem[(w*64 + bl)*33 + i0 + k];
    v[k] = s;
  }
  float* dst = partial + (size_t)(blockIdx.x*4 + blockIdx.y)*2048 + bl*32 + i0;
  *(float4*)(dst)     = make_float4(v[0],v[1],v[2],v[3]);
  *(float4*)(dst + 4) = make_float4(v[4],v[5],v[6],v[7]);
}

// Fused reduce (sum 192 chunk-partials) + squash (16-lane shfl butterfly).
template<bool HALF>
__global__ __launch_bounds__(256) void kred(const float* __restrict__ partial,
                                            float* __restrict__ dst)
{
  const int t = blockIdx.x*256 + threadIdx.x;     // grid 32 -> 8192
  const int btile = t >> 11, q = t & 2047;
  const float* p = partial + (size_t)btile*2048 + q;
  float s = 0.f;
  #pragma unroll 8
  for (int cx=0; cx<CGX; ++cx) s += p[(size_t)cx*8192];
  if (HALF) s *= 0.5f;
  float n2 = s*s;
  #pragma unroll
  for (int m=1; m<16; m<<=1) n2 += __shfl_xor(n2, m);
  const float f = (n2/(1.f+n2)) * rsqrtf(n2 + 1e-9f);
  dst[t] = s * f;
}

// ---------------- fallback: R5 monolithic (no ws) ----------------
#define NT 512
__global__ __launch_bounds__(NT) void kmono(const float* __restrict__ x,
                                            const float* __restrict__ W,
                                            float* __restrict__ out)
{
  const int b    = blockIdx.x;
  const int tid  = threadIdx.x;
  const int wv   = tid >> 6;
  const int lane = tid & 63;
  __shared__ float wred[8*33];
  __shared__ float vsh[32];

  float acc[32];
  #pragma unroll
  for (int i=0;i<32;++i) acc[i]=0.f;
  for (int n = tid; n < N_; n += NT){
    const float4 xa = *(const float4*)(x + ((size_t)b*N_ + n)*D_);
    const float4 xb = *(const float4*)(x + ((size_t)b*N_ + n)*D_ + 4);
    #pragma unroll
    for (int j=0;j<J_;++j){
      const float* wp = W + ((size_t)j*N_ + n)*(E_*D_);
      #pragma unroll
      for (int e=0;e<E_;++e){
        const float4 wa = *(const float4*)(wp + e*8);
        const float4 wb = *(const float4*)(wp + e*8 + 4);
        float a = acc[j*16+e];
        a = fmaf(wa.x,xa.x,a); a = fmaf(wa.y,xa.y,a); a = fmaf(wa.z,xa.z,a); a = fmaf(wa.w,xa.w,a);
        a = fmaf(wb.x,xb.x,a); a = fmaf(wb.y,xb.y,a); a = fmaf(wb.z,xb.z,a); a = fmaf(wb.w,xb.w,a);
        acc[j*16+e] = a;
      }
    }
  }
  #pragma unroll
  for (int i=0;i<32;++i){
    float v = acc[i];
    #pragma unroll
    for (int off=32; off; off>>=1) v += __shfl_xor(v, off);
    acc[i] = v;
  }
  if (lane == 0){
    #pragma unroll
    for (int i=0;i<32;++i) wred[wv*33 + i] = acc[i];
  }
  __syncthreads();
  if (tid < 32){
    float s = 0.f;
    #pragma unroll
    for (int w=0;w<8;++w) s += wred[w*33 + tid];
    wred[tid] = 0.5f * s;
  }
  __syncthreads();
  if (tid < 32){
    const int j = tid >> 4; float n2 = 0.f;
    #pragma unroll
    for (int e=0;e<16;++e){ const float sv = wred[j*16+e]; n2 = fmaf(sv,sv,n2); }
    vsh[tid] = wred[tid] * (n2/(1.f+n2)) * rsqrtf(n2 + 1e-9f);
  }
  __syncthreads();
  float vv[32];
  #pragma unroll
  for (int i=0;i<32;++i) vv[i] = vsh[i];

  #pragma unroll
  for (int i=0;i<32;++i) acc[i]=0.f;
  for (int n = tid; n < N_; n += NT){
    const float4 xa = *(const float4*)(x + ((size_t)b*N_ + n)*D_);
    const float4 xb = *(const float4*)(x + ((size_t)b*N_ + n)*D_ + 4);
    float u[32];
    #pragma unroll
    for (int j=0;j<J_;++j){
      const float* wp = W + ((size_t)j*N_ + n)*(E_*D_);
      #pragma unroll
      for (int e=0;e<E_;++e){
        const float4 wa = *(const float4*)(wp + e*8);
        const float4 wb = *(const float4*)(wp + e*8 + 4);
        float a;
        a = wa.x*xa.x; a = fmaf(wa.y,xa.y,a); a = fmaf(wa.z,xa.z,a); a = fmaf(wa.w,xa.w,a);
        a = fmaf(wb.x,xb.x,a); a = fmaf(wb.y,xb.y,a); a = fmaf(wb.z,xb.z,a); a = fmaf(wb.w,xb.w,a);
        u[j*16+e] = a;
      }
    }
    float l0=0.f, l1=0.f;
    #pragma unroll
    for (int e=0;e<16;++e){ l0 = fmaf(vv[e],u[e],l0); l1 = fmaf(vv[16+e],u[16+e],l1); }
    const float c0 = 1.f/(1.f + __expf(l1 - l0));
    const float c1 = 1.f - c0;
    #pragma unroll
    for (int e=0;e<16;++e){ acc[e] = fmaf(c0,u[e],acc[e]); acc[16+e] = fmaf(c1,u[16+e],acc[16+e]); }
  }
  #pragma unroll
  for (int i=0;i<32;++i){
    float v = acc[i];
    #pragma unroll
    for (int off=32; off; off>>=1) v += __shfl_xor(v, off);
    acc[i] = v;
  }
  __syncthreads();
  if (lane == 0){
    #pragma unroll
    for (int i=0;i<32;++i) wred[wv*33 + i] = acc[i];
  }
  __syncthreads();
  if (tid < 32){
    float s = 0.f;
    #pragma unroll
    for (int w=0;w<8;++w) s += wred[w*33 + tid];
    wred[tid] = s;
  }
  __syncthreads();
  if (tid < 32){
    const int j = tid >> 4; float n2 = 0.f;
    #pragma unroll
    for (int e=0;e<16;++e){ const float sv = wred[j*16+e]; n2 = fmaf(sv,sv,n2); }
    out[(size_t)b*32 + tid] = wred[tid] * (n2/(1.f+n2)) * rsqrtf(n2 + 1e-9f);
  }
}

extern "C" void kernel_launch(void* const* d_in, const int* in_sizes, int n_in,
                              void* d_out, int out_size, void* d_ws, size_t ws_size,
                              hipStream_t stream)
{
  const float* x = (const float*)d_in[0];   // [256,6912,8]
  const float* W = (const float*)d_in[1];   // [2,6912,16,8]
  if (n_in >= 2 && in_sizes[0] < in_sizes[1]){
    x = (const float*)d_in[1]; W = (const float*)d_in[0];
  }
  float* out = (float*)d_out;               // fp32 [256,2,16]

  const size_t need_main = (size_t)(8192 + 768*2048) * sizeof(float);  // ~6.1 MB

  if (ws_size >= need_main){
    float* wsf     = (float*)d_ws;
    float* v1      = wsf;           // 8192 floats
    float* partial = wsf + 8192;    // 768*2048 floats
    kpass1<<<dim3(CGX,4), 256, 0, stream>>>(x, W, partial);
    kred<true ><<<32, 256, 0, stream>>>(partial, v1);
    kpass2<<<dim3(CGX,4), 256, 0, stream>>>(x, W, v1, partial);
    kred<false><<<32, 256, 0, stream>>>(partial, out);
  } else {
    kmono<<<B_, NT, 0, stream>>>(x, W, out);
  }
}

// Round 10
// 162.178 us; speedup vs baseline: 1.1817x; 1.1817x over previous
//
#include <hip/hip_runtime.h>

// Capsule routing: B=256, J=2, N=6912, E=16, D=8, 2 routing iters. All fp32.
//   pass1: s1[b,j,e] = sum_n u_hat;  v1 = squash(0.5*s1)
//   pass2: l[j,n] = sum_e v1*u_hat; c = sigmoid(l0-l1); s2 = sum_n c*u_hat
//   out = squash(s2) fp32 [256,2,16].
// R10: R9's xa[9]/xb[9] prefetch spilled to scratch (WRITE_SIZE 74MB == 57MB
// spill + 6MB partials; VGPR 84). Fix: rolling depth-2 x prefetch (4 float4
// live) + unroll-1 n-loop. W stays staged in LDS (36KB/block, wave-uniform
// ds_read broadcast). Non-atomic partials + fused reduce/squash (proven R8).
#define B_ 256
#define J_ 2
#define N_ 6912
#define E_ 16
#define D_ 8
#define NPW 9     // n per wave
#define NB 36     // n per block (4 waves)
#define CGX 192   // grid (CGX,4); 768 blocks; blockLinear = cx*4 + btile

// ---------------- main path ----------------

// grid (CGX, 4): blockIdx.y = btile (64 b), 4 waves = 4 n-chunks of NPW.
__global__ __launch_bounds__(256, 3) void kpass1(const float* __restrict__ x,
                                                 const float* __restrict__ W,
                                                 float* __restrict__ partial)
{
  __shared__ float smem[9216];   // 36KB: W slice, then reduction scratch
  const int tid  = threadIdx.x;
  const int lane = tid & 63;
  const int wv   = __builtin_amdgcn_readfirstlane(tid >> 6);
  const int b    = blockIdx.y*64 + lane;
  const int nb0  = blockIdx.x * NB;

  const float* xp = x + ((size_t)b*N_ + nb0 + wv*NPW)*D_;
  // rolling depth-2 prefetch (16 VGPRs, no spill)
  float4 pa0 = *(const float4*)(xp + 0);
  float4 pb0 = *(const float4*)(xp + 4);
  float4 pa1 = *(const float4*)(xp + 8);
  float4 pb1 = *(const float4*)(xp + 12);

  // stage W[j=0..1][nb0..nb0+35][16][8] -> smem (2 contiguous 18KB segments)
  float4 wbuf[9];
  #pragma unroll
  for (int k=0;k<9;++k){
    const int idx = k*256 + tid;            // float4 idx 0..2303
    const int j   = (idx >= 1152) ? 1 : 0;
    const int r4  = idx - j*1152;
    wbuf[k] = *(const float4*)(W + ((size_t)j*N_ + nb0)*(E_*D_) + (size_t)r4*4);
  }
  #pragma unroll
  for (int k=0;k<9;++k)
    *(float4*)(smem + (size_t)(k*256 + tid)*4) = wbuf[k];
  __syncthreads();

  float acc[32];
  #pragma unroll
  for (int i=0;i<32;++i) acc[i]=0.f;

  #pragma unroll 1
  for (int ni=0; ni<9; ++ni){
    const float4 va = pa0, vb = pb0;
    pa0 = pa1; pb0 = pb1;
    if (ni < 7){
      pa1 = *(const float4*)(xp + (ni+2)*8);
      pb1 = *(const float4*)(xp + (ni+2)*8 + 4);
    }
    const int nl = wv*NPW + ni;             // local n (wave-uniform)
    #pragma unroll
    for (int j=0;j<J_;++j){
      const float* wp = smem + (j*NB + nl)*(E_*D_);   // uniform: broadcast
      #pragma unroll
      for (int e=0;e<E_;++e){
        const float4 wa = *(const float4*)(wp + e*8);
        const float4 wb = *(const float4*)(wp + e*8 + 4);
        float a = acc[j*16+e];
        a = fmaf(wa.x, va.x, a); a = fmaf(wa.y, va.y, a);
        a = fmaf(wa.z, va.z, a); a = fmaf(wa.w, va.w, a);
        a = fmaf(wb.x, vb.x, a); a = fmaf(wb.y, vb.y, a);
        a = fmaf(wb.z, vb.z, a); a = fmaf(wb.w, vb.w, a);
        acc[j*16+e] = a;
      }
    }
  }

  // block reduction (reuse smem), then coalesced non-atomic partial store
  __syncthreads();
  #pragma unroll
  for (int i=0;i<32;++i) smem[tid*33 + i] = acc[i];
  __syncthreads();
  const int bl = tid >> 2;
  const int i0 = (tid & 3) * 8;
  float v[8];
  #pragma unroll
  for (int k=0;k<8;++k){
    float s = 0.f;
    #pragma unroll
    for (int w=0; w<4; ++w) s += smem[(w*64 + bl)*33 + i0 + k];
    v[k] = s;
  }
  float* dst = partial + (size_t)(blockIdx.x*4 + blockIdx.y)*2048 + bl*32 + i0;
  *(float4*)(dst)     = make_float4(v[0],v[1],v[2],v[3]);
  *(float4*)(dst + 4) = make_float4(v[4],v[5],v[6],v[7]);
}

__global__ __launch_bounds__(256, 3) void kpass2(const float* __restrict__ x,
                                                 const float* __restrict__ W,
                                                 const float* __restrict__ v1,
                                                 float* __restrict__ partial)
{
  __shared__ float smem[9216];
  const int tid  = threadIdx.x;
  const int lane = tid & 63;
  const int wv   = __builtin_amdgcn_readfirstlane(tid >> 6);
  const int b    = blockIdx.y*64 + lane;
  const int nb0  = blockIdx.x * NB;

  const float* xp = x + ((size_t)b*N_ + nb0 + wv*NPW)*D_;
  float4 pa0 = *(const float4*)(xp + 0);
  float4 pb0 = *(const float4*)(xp + 4);
  float4 pa1 = *(const float4*)(xp + 8);
  float4 pb1 = *(const float4*)(xp + 12);

  float4 wbuf[9];
  #pragma unroll
  for (int k=0;k<9;++k){
    const int idx = k*256 + tid;
    const int j   = (idx >= 1152) ? 1 : 0;
    const int r4  = idx - j*1152;
    wbuf[k] = *(const float4*)(W + ((size_t)j*N_ + nb0)*(E_*D_) + (size_t)r4*4);
  }
  #pragma unroll
  for (int k=0;k<9;++k)
    *(float4*)(smem + (size_t)(k*256 + tid)*4) = wbuf[k];

  float vv[32];
  {
    const float4* vp = (const float4*)(v1 + (size_t)b*32);
    #pragma unroll
    for (int q=0;q<8;++q){
      const float4 t4 = vp[q];
      vv[q*4+0]=t4.x; vv[q*4+1]=t4.y; vv[q*4+2]=t4.z; vv[q*4+3]=t4.w;
    }
  }
  __syncthreads();

  float acc[32];
  #pragma unroll
  for (int i=0;i<32;++i) acc[i]=0.f;

  #pragma unroll 1
  for (int ni=0; ni<9; ++ni){
    const float4 va = pa0, vb = pb0;
    pa0 = pa1; pb0 = pb1;
    if (ni < 7){
      pa1 = *(const float4*)(xp + (ni+2)*8);
      pb1 = *(const float4*)(xp + (ni+2)*8 + 4);
    }
    const int nl = wv*NPW + ni;
    float u[32];
    #pragma unroll
    for (int j=0;j<J_;++j){
      const float* wp = smem + (j*NB + nl)*(E_*D_);
      #pragma unroll
      for (int e=0;e<E_;++e){
        const float4 wa = *(const float4*)(wp + e*8);
        const float4 wb = *(const float4*)(wp + e*8 + 4);
        float a;
        a = wa.x*va.x;           a = fmaf(wa.y, va.y, a);
        a = fmaf(wa.z, va.z, a); a = fmaf(wa.w, va.w, a);
        a = fmaf(wb.x, vb.x, a); a = fmaf(wb.y, vb.y, a);
        a = fmaf(wb.z, vb.z, a); a = fmaf(wb.w, vb.w, a);
        u[j*16+e] = a;
      }
    }
    float l0=0.f, l1=0.f;
    #pragma unroll
    for (int e=0;e<E_;++e){
      l0 = fmaf(vv[e],    u[e],    l0);
      l1 = fmaf(vv[16+e], u[16+e], l1);
    }
    const float c0 = 1.f/(1.f + __expf(l1 - l0));   // softmax over 2 caps
    const float c1 = 1.f - c0;
    #pragma unroll
    for (int e=0;e<E_;++e){
      acc[e]    = fmaf(c0, u[e],    acc[e]);
      acc[16+e] = fmaf(c1, u[16+e], acc[16+e]);
    }
  }

  __syncthreads();
  #pragma unroll
  for (int i=0;i<32;++i) smem[tid*33 + i] = acc[i];
  __syncthreads();
  const int bl = tid >> 2;
  const int i0 = (tid & 3) * 8;
  float v[8];
  #pragma unroll
  for (int k=0;k<8;++k){
    float s = 0.f;
    #pragma unroll
    for (int w=0; w<4; ++w) s += smem[(w*64 + bl)*33 + i0 + k];
    v[k] = s;
  }
  float* dst = partial + (size_t)(blockIdx.x*4 + blockIdx.y)*2048 + bl*32 + i0;
  *(float4*)(dst)     = make_float4(v[0],v[1],v[2],v[3]);
  *(float4*)(dst + 4) = make_float4(v[4],v[5],v[6],v[7]);
}

// Fused reduce (sum 192 chunk-partials) + squash (16-lane shfl butterfly).
template<bool HALF>
__global__ __launch_bounds__(256) void kred(const float* __restrict__ partial,
                                            float* __restrict__ dst)
{
  const int t = blockIdx.x*256 + threadIdx.x;     // grid 32 -> 8192
  const int btile = t >> 11, q = t & 2047;
  const float* p = partial + (size_t)btile*2048 + q;
  float s = 0.f;
  #pragma unroll 8
  for (int cx=0; cx<CGX; ++cx) s += p[(size_t)cx*8192];
  if (HALF) s *= 0.5f;
  float n2 = s*s;
  #pragma unroll
  for (int m=1; m<16; m<<=1) n2 += __shfl_xor(n2, m);
  const float f = (n2/(1.f+n2)) * rsqrtf(n2 + 1e-9f);
  dst[t] = s * f;
}

// ---------------- fallback: R5 monolithic (no ws) ----------------
#define NT 512
__global__ __launch_bounds__(NT) void kmono(const float* __restrict__ x,
                                            const float* __restrict__ W,
                                            float* __restrict__ out)
{
  const int b    = blockIdx.x;
  const int tid  = threadIdx.x;
  const int wv   = tid >> 6;
  const int lane = tid & 63;
  __shared__ float wred[8*33];
  __shared__ float vsh[32];

  float acc[32];
  #pragma unroll
  for (int i=0;i<32;++i) acc[i]=0.f;
  for (int n = tid; n < N_; n += NT){
    const float4 xa = *(const float4*)(x + ((size_t)b*N_ + n)*D_);
    const float4 xb = *(const float4*)(x + ((size_t)b*N_ + n)*D_ + 4);
    #pragma unroll
    for (int j=0;j<J_;++j){
      const float* wp = W + ((size_t)j*N_ + n)*(E_*D_);
      #pragma unroll
      for (int e=0;e<E_;++e){
        const float4 wa = *(const float4*)(wp + e*8);
        const float4 wb = *(const float4*)(wp + e*8 + 4);
        float a = acc[j*16+e];
        a = fmaf(wa.x,xa.x,a); a = fmaf(wa.y,xa.y,a); a = fmaf(wa.z,xa.z,a); a = fmaf(wa.w,xa.w,a);
        a = fmaf(wb.x,xb.x,a); a = fmaf(wb.y,xb.y,a); a = fmaf(wb.z,xb.z,a); a = fmaf(wb.w,xb.w,a);
        acc[j*16+e] = a;
      }
    }
  }
  #pragma unroll
  for (int i=0;i<32;++i){
    float v = acc[i];
    #pragma unroll
    for (int off=32; off; off>>=1) v += __shfl_xor(v, off);
    acc[i] = v;
  }
  if (lane == 0){
    #pragma unroll
    for (int i=0;i<32;++i) wred[wv*33 + i] = acc[i];
  }
  __syncthreads();
  if (tid < 32){
    float s = 0.f;
    #pragma unroll
    for (int w=0;w<8;++w) s += wred[w*33 + tid];
    wred[tid] = 0.5f * s;
  }
  __syncthreads();
  if (tid < 32){
    const int j = tid >> 4; float n2 = 0.f;
    #pragma unroll
    for (int e=0;e<16;++e){ const float sv = wred[j*16+e]; n2 = fmaf(sv,sv,n2); }
    vsh[tid] = wred[tid] * (n2/(1.f+n2)) * rsqrtf(n2 + 1e-9f);
  }
  __syncthreads();
  float vv[32];
  #pragma unroll
  for (int i=0;i<32;++i) vv[i] = vsh[i];

  #pragma unroll
  for (int i=0;i<32;++i) acc[i]=0.f;
  for (int n = tid; n < N_; n += NT){
    const float4 xa = *(const float4*)(x + ((size_t)b*N_ + n)*D_);
    const float4 xb = *(const float4*)(x + ((size_t)b*N_ + n)*D_ + 4);
    float u[32];
    #pragma unroll
    for (int j=0;j<J_;++j){
      const float* wp = W + ((size_t)j*N_ + n)*(E_*D_);
      #pragma unroll
      for (int e=0;e<E_;++e){
        const float4 wa = *(const float4*)(wp + e*8);
        const float4 wb = *(const float4*)(wp + e*8 + 4);
        float a;
        a = wa.x*xa.x; a = fmaf(wa.y,xa.y,a); a = fmaf(wa.z,xa.z,a); a = fmaf(wa.w,xa.w,a);
        a = fmaf(wb.x,xb.x,a); a = fmaf(wb.y,xb.y,a); a = fmaf(wb.z,xb.z,a); a = fmaf(wb.w,xb.w,a);
        u[j*16+e] = a;
      }
    }
    float l0=0.f, l1=0.f;
    #pragma unroll
    for (int e=0;e<16;++e){ l0 = fmaf(vv[e],u[e],l0); l1 = fmaf(vv[16+e],u[16+e],l1); }
    const float c0 = 1.f/(1.f + __expf(l1 - l0));
    const float c1 = 1.f - c0;
    #pragma unroll
    for (int e=0;e<16;++e){ acc[e] = fmaf(c0,u[e],acc[e]); acc[16+e] = fmaf(c1,u[16+e],acc[16+e]); }
  }
  #pragma unroll
  for (int i=0;i<32;++i){
    float v = acc[i];
    #pragma unroll
    for (int off=32; off; off>>=1) v += __shfl_xor(v, off);
    acc[i] = v;
  }
  __syncthreads();
  if (lane == 0){
    #pragma unroll
    for (int i=0;i<32;++i) wred[wv*33 + i] = acc[i];
  }
  __syncthreads();
  if (tid < 32){
    float s = 0.f;
    #pragma unroll
    for (int w=0;w<8;++w) s += wred[w*33 + tid];
    wred[tid] = s;
  }
  __syncthreads();
  if (tid < 32){
    const int j = tid >> 4; float n2 = 0.f;
    #pragma unroll
    for (int e=0;e<16;++e){ const float sv = wred[j*16+e]; n2 = fmaf(sv,sv,n2); }
    out[(size_t)b*32 + tid] = wred[tid] * (n2/(1.f+n2)) * rsqrtf(n2 + 1e-9f);
  }
}

extern "C" void kernel_launch(void* const* d_in, const int* in_sizes, int n_in,
                              void* d_out, int out_size, void* d_ws, size_t ws_size,
                              hipStream_t stream)
{
  const float* x = (const float*)d_in[0];   // [256,6912,8]
  const float* W = (const float*)d_in[1];   // [2,6912,16,8]
  if (n_in >= 2 && in_sizes[0] < in_sizes[1]){
    x = (const float*)d_in[1]; W = (const float*)d_in[0];
  }
  float* out = (float*)d_out;               // fp32 [256,2,16]

  const size_t need_main = (size_t)(8192 + 768*2048) * sizeof(float);  // ~6.1 MB

  if (ws_size >= need_main){
    float* wsf     = (float*)d_ws;
    float* v1      = wsf;           // 8192 floats
    float* partial = wsf + 8192;    // 768*2048 floats
    kpass1<<<dim3(CGX,4), 256, 0, stream>>>(x, W, partial);
    kred<true ><<<32, 256, 0, stream>>>(partial, v1);
    kpass2<<<dim3(CGX,4), 256, 0, stream>>>(x, W, v1, partial);
    kred<false><<<32, 256, 0, stream>>>(partial, out);
  } else {
    kmono<<<B_, NT, 0, stream>>>(x, W, out);
  }
}